// Round 7
// baseline (371.392 us; speedup 1.0000x reference)
//
#include <hip/hip_runtime.h>
#include <hip/hip_bf16.h>

// ---------------- problem constants (match setup_inputs) ----------------
#define T_TOK 4096
#define H_DIM 1024
#define E_NUM 8
#define I_DIM 3584
#define NPAIR (T_TOK * 2)   // top_k = 2
#define MAX_RT 72           // worst-case total row tiles: sum ceil(cnt_e/128) <= 64+7

#define BM 128
#define BN 256
#define BK 64

typedef __attribute__((ext_vector_type(8))) short bf16x8;
typedef __attribute__((ext_vector_type(4))) float f32x4;
typedef __attribute__((ext_vector_type(8))) unsigned short ushort8_t;
typedef __attribute__((ext_vector_type(4))) unsigned short ushort4_t;

// RNE fp32 -> bf16
__device__ __forceinline__ unsigned short f2bf(float x) {
  unsigned int u = __float_as_uint(x);
  unsigned int r = (u + 0x7FFFu + ((u >> 16) & 1u)) >> 16;
  return (unsigned short)r;
}

// async 16B global -> LDS (dest: wave-uniform base, HW adds lane*16)
__device__ __forceinline__ void gload16(const void* g, unsigned short* l) {
  __builtin_amdgcn_global_load_lds(
      (const __attribute__((address_space(1))) void*)g,
      (__attribute__((address_space(3))) void*)l, 16, 0, 0);
}

// ---------------- transpose + fp32->bf16 convert ----------------
__global__ void transpose_cvt(const float* __restrict__ src,
                              unsigned short* __restrict__ dst, int R, int C) {
  __shared__ float tile[64][65];
  const int e = blockIdx.z;
  const int c0 = blockIdx.x * 64, r0 = blockIdx.y * 64;
  const float* s = src + (size_t)e * R * C;
  unsigned short* d = dst + (size_t)e * R * C;
  const int th = threadIdx.x;
  const int tr = th >> 4;
  const int tc4 = (th & 15) * 4;
#pragma unroll
  for (int it = 0; it < 4; ++it) {
    const int r = it * 16 + tr;
    float4 v = *reinterpret_cast<const float4*>(s + (size_t)(r0 + r) * C + c0 + tc4);
    tile[r][tc4] = v.x; tile[r][tc4 + 1] = v.y; tile[r][tc4 + 2] = v.z; tile[r][tc4 + 3] = v.w;
  }
  __syncthreads();
  const int wc = th >> 3;
  const int wr = (th & 7) * 8;
#pragma unroll
  for (int it = 0; it < 2; ++it) {
    const int c = it * 32 + wc;
    ushort8_t o;
#pragma unroll
    for (int j = 0; j < 8; ++j) o[j] = f2bf(tile[wr + j][c]);
    *reinterpret_cast<ushort8_t*>(d + (size_t)(c0 + c) * R + r0 + wr) = o;
  }
}

// ---------------- router: LDS-staged gw, float4 hs, LDS-aggregated counts --
__global__ void router_kernel(const float* __restrict__ hs, const float* __restrict__ gw,
                              unsigned short* __restrict__ hsb,
                              int* __restrict__ eid, float* __restrict__ wgt,
                              int* __restrict__ counts) {
  __shared__ float s_gw[8192];
  __shared__ int s_cnt[E_NUM];
  const int th = threadIdx.x;
  for (int u = th; u < 2048; u += 256) {
    const f32x4 v = *reinterpret_cast<const f32x4*>(gw + u * 4);
    *reinterpret_cast<f32x4*>(&s_gw[(u ^ ((u >> 3) & 7)) * 4]) = v;
  }
  if (th < E_NUM) s_cnt[th] = 0;
  __syncthreads();

  const int l = th & 63, w = th >> 6;
#pragma unroll 1
  for (int tt = 0; tt < 4; ++tt) {
    const int t = blockIdx.x * 16 + w * 4 + tt;
    const float* hrow = hs + (size_t)t * H_DIM;
    unsigned short* brow = hsb + (size_t)t * H_DIM;
    float acc[E_NUM];
#pragma unroll
    for (int e = 0; e < E_NUM; ++e) acc[e] = 0.f;
#pragma unroll
    for (int i = 0; i < 4; ++i) {
      const int h0 = i * 256 + l * 4;
      const f32x4 x = *reinterpret_cast<const f32x4*>(hrow + h0);
      ushort4_t o = { f2bf(x[0]), f2bf(x[1]), f2bf(x[2]), f2bf(x[3]) };
      *reinterpret_cast<ushort4_t*>(brow + h0) = o;
#pragma unroll
      for (int j = 0; j < 4; ++j) {
        const int h = h0 + j;
        const int p0 = (h * 2) ^ ((h >> 2) & 7);
        const f32x4 g0 = *reinterpret_cast<const f32x4*>(&s_gw[p0 * 4]);
        const f32x4 g1 = *reinterpret_cast<const f32x4*>(&s_gw[(p0 ^ 1) * 4]);
        acc[0] += x[j] * g0[0]; acc[1] += x[j] * g0[1];
        acc[2] += x[j] * g0[2]; acc[3] += x[j] * g0[3];
        acc[4] += x[j] * g1[0]; acc[5] += x[j] * g1[1];
        acc[6] += x[j] * g1[2]; acc[7] += x[j] * g1[3];
      }
    }
#pragma unroll
    for (int e = 0; e < E_NUM; ++e) {
#pragma unroll
      for (int off = 1; off < 64; off <<= 1) acc[e] += __shfl_xor(acc[e], off);
    }
    if (l == 0) {
      int i1 = 0;
#pragma unroll
      for (int e = 1; e < E_NUM; ++e) if (acc[e] > acc[i1]) i1 = e;
      int i2 = (i1 == 0) ? 1 : 0;
#pragma unroll
      for (int e = 0; e < E_NUM; ++e) if (e != i1 && acc[e] > acc[i2]) i2 = e;
      const float e2 = __expf(acc[i2] - acc[i1]);
      const float inv = 1.f / (1.f + e2);
      eid[t * 2] = i1;     wgt[t * 2] = inv;
      eid[t * 2 + 1] = i2; wgt[t * 2 + 1] = e2 * inv;
      atomicAdd(&s_cnt[i1], 1);
      atomicAdd(&s_cnt[i2], 1);
    }
  }
  __syncthreads();
  if (th < E_NUM && s_cnt[th] > 0) atomicAdd(&counts[th], s_cnt[th]);
}

// ---------------- scatter: block-local histogram + range reservation -------
__global__ void scatter_kernel(const int* __restrict__ eid, const int* __restrict__ counts,
                               int* __restrict__ fill, int* __restrict__ rowmap) {
  __shared__ int hist[E_NUM], base[E_NUM];
  const int th = threadIdx.x;
  const int p = blockIdx.x * 256 + th;
  if (th < E_NUM) hist[th] = 0;
  __syncthreads();
  const int e = eid[p];
  const int rloc = atomicAdd(&hist[e], 1);
  __syncthreads();
  if (th < E_NUM) base[th] = (hist[th] > 0) ? atomicAdd(&fill[th], hist[th]) : 0;
  __syncthreads();
  int off = 0;
#pragma unroll
  for (int i = 0; i < E_NUM; ++i) off += (i < e) ? counts[i] : 0;
  rowmap[off + base[e] + rloc] = p;
}

// ---------------- grouped GEMM: 128x256, 8 waves, 3-ring LDS, vmcnt(6) -----
// MODE 0: A = gathered hs bf16 (K=1024), B = w1t [E][I][H], C = silu -> act
// MODE 1: A = act bf16 (K-split 4 x 896), B = w2t [E][H][I], C -> atomicAdd
template <int MODE, int NCT, int KS, int KBLK>
__launch_bounds__(512, 2)
__global__ void moe_gemm(const unsigned short* __restrict__ hsb,
                         const unsigned short* __restrict__ wt,
                         const unsigned short* __restrict__ act_in,
                         unsigned short* __restrict__ act_out,
                         float* __restrict__ out,
                         const int* __restrict__ counts,
                         const int* __restrict__ rowmap,
                         const float* __restrict__ wgt) {
  constexpr int KROW = (MODE == 0) ? H_DIM : I_DIM;  // row length of A and B
  constexpr int NT = KBLK / BK;                       // K-tiles per block
  constexpr int NWG = MAX_RT * NCT * KS;              // %8==0 (1008 / 1152)
  constexpr int RING = 24576;                         // shorts: A 8192 + B 16384

  __shared__ unsigned short S[3 * RING];              // 144 KB
  __shared__ int s_pair[BM];
  __shared__ float s_w[BM];

  // T1 bijective XCD swizzle; ct fastest within chunk (A-tile L2-resident)
  const int bid = blockIdx.x;
  const int wgid = (bid & 7) * (NWG / 8) + (bid >> 3);
  const int rt = wgid / (NCT * KS);
  const int rem = wgid % (NCT * KS);
  const int ct = rem % NCT;
  const int kbase = (rem / NCT) * KBLK;

  // expert walk from counts (prefix on the fly)
  int e = -1, loc_rt = 0, off_e = 0, cnt = 0;
  {
    int acc_t = 0, off = 0;
#pragma unroll
    for (int ee = 0; ee < E_NUM; ++ee) {
      const int c = counts[ee];
      const int nt = (c + BM - 1) >> 7;
      if (e < 0 && rt < acc_t + nt) { e = ee; loc_rt = rt - acc_t; off_e = off; cnt = c; }
      acc_t += nt; off += c;
    }
  }
  if (e < 0) return;

  const int cnt_local = min(BM, cnt - loc_rt * BM);
  const int r_base = off_e + loc_rt * BM;
  const int th = threadIdx.x;
  const int lane = th & 63, wid = th >> 6;

  if (MODE == 1 && th < BM) {
    int r = loc_rt * BM + th;
    if (r >= cnt) r = cnt - 1;
    const int p = rowmap[off_e + r];
    s_pair[th] = p;
    s_w[th] = wgt[p];
  }

  const int n0 = ct * BN;
  const unsigned short* wbase =
      wt + (size_t)e * ((size_t)I_DIM * H_DIM) + (size_t)n0 * KROW + kbase;

  // staging: thread covers (row = base + th/8 within 64-row group, chunk th%8)
  // LDS dest linear; source chunk pre-swizzled: cg = (th&7) ^ (row&7)
  const int srow8 = lane >> 3;          // 0..7  (row mod 8 within wave group)
  const int cg = (lane & 7) ^ srow8;
  const char* aptr[2];
  const char* bptr[4];
#pragma unroll
  for (int i = 0; i < 2; ++i) {
    const int r = i * 64 + wid * 8 + srow8;       // 0..127
    const int rr = (r < cnt_local) ? r : (cnt_local - 1);
    if (MODE == 0) {
      const int tok = rowmap[off_e + loc_rt * BM + rr] >> 1;
      aptr[i] = (const char*)(hsb + (size_t)tok * H_DIM + kbase) + cg * 16;
    } else {
      aptr[i] = (const char*)(act_in + (size_t)(r_base + rr) * I_DIM + kbase) + cg * 16;
    }
  }
#pragma unroll
  for (int j = 0; j < 4; ++j) {
    const int r = j * 64 + wid * 8 + srow8;       // 0..255
    bptr[j] = (const char*)(wbase + (size_t)r * KROW) + cg * 16;
  }

#define STG_P0(rg, kb) do {                                     \
    gload16(aptr[0] + (kb), &S[(rg) * RING + wid * 512]);       \
    gload16(aptr[1] + (kb), &S[(rg) * RING + 4096 + wid * 512]);\
    gload16(bptr[0] + (kb), &S[(rg) * RING + 8192 + wid * 512]);} while (0)
#define STG_P1(rg, kb) do {                                     \
    gload16(bptr[1] + (kb), &S[(rg) * RING + 12288 + wid * 512]);\
    gload16(bptr[2] + (kb), &S[(rg) * RING + 16384 + wid * 512]);\
    gload16(bptr[3] + (kb), &S[(rg) * RING + 20480 + wid * 512]);} while (0)

  // wave tiling: 2M x 4N waves, 64x64 per wave (4x4 16x16 frags)
  const int wm = (wid >> 2) * 64;
  const int wn = (wid & 3) * 64;
  const int fr = lane & 15, fq = lane >> 4;
  const int sx = fr & 7;
  const int ck0 = (fq ^ sx) * 8;
  const int ck1 = ((4 + fq) ^ sx) * 8;
  const int arow = (wm + fr) * 64;      // + m*1024
  const int brow = (wn + fr) * 64;      // + n*1024

  f32x4 acc[4][4];
#pragma unroll
  for (int m = 0; m < 4; ++m)
#pragma unroll
    for (int n = 0; n < 4; ++n) acc[m][n] = (f32x4){0.f, 0.f, 0.f, 0.f};

  // prologue: K-tiles 0,1 -> rings 0,1; wait tile0 (tile1's 6 stay in flight)
  STG_P0(0, 0); STG_P1(0, 0);
  STG_P0(1, 128); STG_P1(1, 128);
  asm volatile("s_waitcnt vmcnt(6)" ::: "memory");
  __builtin_amdgcn_s_barrier();

  int rd = 0, wr = 2;
  for (int t = 0; t < NT; ++t) {
    const unsigned short* Ab = &S[rd * RING];
    const unsigned short* Bb = Ab + 8192;
    const int kb2 = (t + 2) * 128;
    const bool stg = (t + 2) < NT;
    // ---- phase 0: k-half 0
    {
      bf16x8 a0[4], b0[4];
#pragma unroll
      for (int m = 0; m < 4; ++m)
        a0[m] = *reinterpret_cast<const bf16x8*>(&Ab[arow + m * 1024 + ck0]);
#pragma unroll
      for (int n = 0; n < 4; ++n)
        b0[n] = *reinterpret_cast<const bf16x8*>(&Bb[brow + n * 1024 + ck0]);
      if (stg) STG_P0(wr, kb2);
      __builtin_amdgcn_s_barrier();
      asm volatile("s_waitcnt lgkmcnt(0)" ::: "memory");
      __builtin_amdgcn_sched_barrier(0);
      __builtin_amdgcn_s_setprio(1);
#pragma unroll
      for (int m = 0; m < 4; ++m)
#pragma unroll
        for (int n = 0; n < 4; ++n)
          acc[m][n] = __builtin_amdgcn_mfma_f32_16x16x32_bf16(a0[m], b0[n], acc[m][n], 0, 0, 0);
      __builtin_amdgcn_s_setprio(0);
      __builtin_amdgcn_s_barrier();
    }
    // ---- phase 1: k-half 1
    {
      bf16x8 a1[4], b1[4];
#pragma unroll
      for (int m = 0; m < 4; ++m)
        a1[m] = *reinterpret_cast<const bf16x8*>(&Ab[arow + m * 1024 + ck1]);
#pragma unroll
      for (int n = 0; n < 4; ++n)
        b1[n] = *reinterpret_cast<const bf16x8*>(&Bb[brow + n * 1024 + ck1]);
      if (stg) STG_P1(wr, kb2);
      __builtin_amdgcn_s_barrier();
      asm volatile("s_waitcnt lgkmcnt(0)" ::: "memory");
      __builtin_amdgcn_sched_barrier(0);
      __builtin_amdgcn_s_setprio(1);
#pragma unroll
      for (int m = 0; m < 4; ++m)
#pragma unroll
        for (int n = 0; n < 4; ++n)
          acc[m][n] = __builtin_amdgcn_mfma_f32_16x16x32_bf16(a1[m], b1[n], acc[m][n], 0, 0, 0);
      __builtin_amdgcn_s_setprio(0);
    }
    // ---- K-tile boundary: tile t+1 landed iff only the 6 just-issued remain
    if (t + 1 < NT) {
      if (stg) asm volatile("s_waitcnt vmcnt(6)" ::: "memory");
      else     asm volatile("s_waitcnt vmcnt(0)" ::: "memory");
      __builtin_amdgcn_sched_barrier(0);
      __builtin_amdgcn_s_barrier();
    }
    rd = (rd == 2) ? 0 : rd + 1;
    wr = (wr == 2) ? 0 : wr + 1;
  }
#undef STG_P0
#undef STG_P1

  // ---- epilogue ----
#pragma unroll
  for (int m = 0; m < 4; ++m) {
    const int row = wm + m * 16 + fq * 4;
#pragma unroll
    for (int n = 0; n < 4; ++n) {
      const int col = n0 + wn + n * 16 + fr;
#pragma unroll
      for (int r2 = 0; r2 < 4; ++r2) {
        const int rw = row + r2;
        if (rw < cnt_local) {
          const float x = acc[m][n][r2];
          if (MODE == 0) {
            const float s = x / (1.f + __expf(-x));   // silu
            act_out[(size_t)(r_base + rw) * I_DIM + col] = f2bf(s);
          } else {
            const int tok = s_pair[rw] >> 1;
            atomicAdd(out + (size_t)tok * H_DIM + col, x * s_w[rw]);
          }
        }
      }
    }
  }
}

// ---------------- launch ----------------
extern "C" void kernel_launch(void* const* d_in, const int* in_sizes, int n_in,
                              void* d_out, int out_size, void* d_ws, size_t ws_size,
                              hipStream_t stream) {
  const float* hs = (const float*)d_in[0];
  const float* gw = (const float*)d_in[1];
  const float* w1 = (const float*)d_in[2];
  const float* w2 = (const float*)d_in[3];
  float* out = (float*)d_out;

  char* ws = (char*)d_ws;
  const size_t WMAT = (size_t)E_NUM * I_DIM * H_DIM * 2;   // 58,720,256 B
  unsigned short* w1t = (unsigned short*)ws;                // [E][I][H] bf16
  unsigned short* w2t = (unsigned short*)(ws + WMAT);       // [E][H][I] bf16
  unsigned short* act = (unsigned short*)(ws + 2 * WMAT);   // [NPAIR][I] bf16
  unsigned short* hsb = (unsigned short*)(ws + 3 * WMAT);   // [T][H] bf16
  char* small = ws + 3 * WMAT + (size_t)T_TOK * H_DIM * 2;
  int* eid = (int*)small;                          // NPAIR
  float* wgt = (float*)(small + NPAIR * 4);        // NPAIR
  int* rowmap = (int*)(small + 2 * NPAIR * 4);     // NPAIR
  int* counts = (int*)(small + 3 * NPAIR * 4);     // 8
  int* fill = counts + 8;                          // 8

  hipMemsetAsync(d_out, 0, (size_t)T_TOK * H_DIM * sizeof(float), stream);
  hipMemsetAsync(counts, 0, 16 * sizeof(int), stream);

  transpose_cvt<<<dim3(I_DIM / 64, H_DIM / 64, E_NUM), 256, 0, stream>>>(w1, w1t, H_DIM, I_DIM);
  transpose_cvt<<<dim3(H_DIM / 64, I_DIM / 64, E_NUM), 256, 0, stream>>>(w2, w2t, I_DIM, H_DIM);

  router_kernel<<<T_TOK / 16, 256, 0, stream>>>(hs, gw, hsb, eid, wgt, counts);
  scatter_kernel<<<NPAIR / 256, 256, 0, stream>>>(eid, counts, fill, rowmap);

  // MODE0: N=3584 -> 14 col tiles; K=1024
  moe_gemm<0, 14, 1, 1024><<<MAX_RT * 14, 512, 0, stream>>>(
      hsb, w1t, nullptr, act, nullptr, counts, rowmap, wgt);
  // MODE1: N=1024 -> 4 col tiles; K=3584 split 4x896 (atomic output)
  moe_gemm<1, 4, 4, 896><<<MAX_RT * 4 * 4, 512, 0, stream>>>(
      hsb, w2t, act, nullptr, out, counts, rowmap, wgt);
}

// Round 8
// 350.279 us; speedup vs baseline: 1.0603x; 1.0603x over previous
//
#include <hip/hip_runtime.h>
#include <hip/hip_bf16.h>

// ---------------- problem constants (match setup_inputs) ----------------
#define T_TOK 4096
#define H_DIM 1024
#define E_NUM 8
#define I_DIM 3584
#define NPAIR (T_TOK * 2)   // top_k = 2
#define MAX_RT 72           // worst-case total row tiles: sum ceil(cnt_e/128) <= 64+7

#define BM 128
#define BN 128
#define BK 64

typedef __attribute__((ext_vector_type(8))) short bf16x8;
typedef __attribute__((ext_vector_type(4))) float f32x4;
typedef __attribute__((ext_vector_type(8))) unsigned short ushort8_t;
typedef __attribute__((ext_vector_type(4))) unsigned short ushort4_t;

// RNE fp32 -> bf16
__device__ __forceinline__ unsigned short f2bf(float x) {
  unsigned int u = __float_as_uint(x);
  unsigned int r = (u + 0x7FFFu + ((u >> 16) & 1u)) >> 16;
  return (unsigned short)r;
}

// async 16B global -> LDS (dest: wave-uniform base, HW adds lane*16)
__device__ __forceinline__ void gload16(const void* g, unsigned short* l) {
  __builtin_amdgcn_global_load_lds(
      (const __attribute__((address_space(1))) void*)g,
      (__attribute__((address_space(3))) void*)l, 16, 0, 0);
}

// ---------------- transpose + fp32->bf16 convert ----------------
__global__ void transpose_cvt(const float* __restrict__ src,
                              unsigned short* __restrict__ dst, int R, int C) {
  __shared__ float tile[64][65];
  const int e = blockIdx.z;
  const int c0 = blockIdx.x * 64, r0 = blockIdx.y * 64;
  const float* s = src + (size_t)e * R * C;
  unsigned short* d = dst + (size_t)e * R * C;
  const int th = threadIdx.x;
  const int tr = th >> 4;
  const int tc4 = (th & 15) * 4;
#pragma unroll
  for (int it = 0; it < 4; ++it) {
    const int r = it * 16 + tr;
    float4 v = *reinterpret_cast<const float4*>(s + (size_t)(r0 + r) * C + c0 + tc4);
    tile[r][tc4] = v.x; tile[r][tc4 + 1] = v.y; tile[r][tc4 + 2] = v.z; tile[r][tc4 + 3] = v.w;
  }
  __syncthreads();
  const int wc = th >> 3;
  const int wr = (th & 7) * 8;
#pragma unroll
  for (int it = 0; it < 2; ++it) {
    const int c = it * 32 + wc;
    ushort8_t o;
#pragma unroll
    for (int j = 0; j < 8; ++j) o[j] = f2bf(tile[wr + j][c]);
    *reinterpret_cast<ushort8_t*>(d + (size_t)(c0 + c) * R + r0 + wr) = o;
  }
}

// ---------------- router: LDS-staged gw, float4 hs, LDS-aggregated counts --
__global__ void router_kernel(const float* __restrict__ hs, const float* __restrict__ gw,
                              unsigned short* __restrict__ hsb,
                              int* __restrict__ eid, float* __restrict__ wgt,
                              int* __restrict__ counts) {
  __shared__ float s_gw[8192];
  __shared__ int s_cnt[E_NUM];
  const int th = threadIdx.x;
  for (int u = th; u < 2048; u += 256) {
    const f32x4 v = *reinterpret_cast<const f32x4*>(gw + u * 4);
    *reinterpret_cast<f32x4*>(&s_gw[(u ^ ((u >> 3) & 7)) * 4]) = v;
  }
  if (th < E_NUM) s_cnt[th] = 0;
  __syncthreads();

  const int l = th & 63, w = th >> 6;
#pragma unroll 1
  for (int tt = 0; tt < 4; ++tt) {
    const int t = blockIdx.x * 16 + w * 4 + tt;
    const float* hrow = hs + (size_t)t * H_DIM;
    unsigned short* brow = hsb + (size_t)t * H_DIM;
    float acc[E_NUM];
#pragma unroll
    for (int e = 0; e < E_NUM; ++e) acc[e] = 0.f;
#pragma unroll
    for (int i = 0; i < 4; ++i) {
      const int h0 = i * 256 + l * 4;
      const f32x4 x = *reinterpret_cast<const f32x4*>(hrow + h0);
      ushort4_t o = { f2bf(x[0]), f2bf(x[1]), f2bf(x[2]), f2bf(x[3]) };
      *reinterpret_cast<ushort4_t*>(brow + h0) = o;
#pragma unroll
      for (int j = 0; j < 4; ++j) {
        const int h = h0 + j;
        const int p0 = (h * 2) ^ ((h >> 2) & 7);
        const f32x4 g0 = *reinterpret_cast<const f32x4*>(&s_gw[p0 * 4]);
        const f32x4 g1 = *reinterpret_cast<const f32x4*>(&s_gw[(p0 ^ 1) * 4]);
        acc[0] += x[j] * g0[0]; acc[1] += x[j] * g0[1];
        acc[2] += x[j] * g0[2]; acc[3] += x[j] * g0[3];
        acc[4] += x[j] * g1[0]; acc[5] += x[j] * g1[1];
        acc[6] += x[j] * g1[2]; acc[7] += x[j] * g1[3];
      }
    }
#pragma unroll
    for (int e = 0; e < E_NUM; ++e) {
#pragma unroll
      for (int off = 1; off < 64; off <<= 1) acc[e] += __shfl_xor(acc[e], off);
    }
    if (l == 0) {
      int i1 = 0;
#pragma unroll
      for (int e = 1; e < E_NUM; ++e) if (acc[e] > acc[i1]) i1 = e;
      int i2 = (i1 == 0) ? 1 : 0;
#pragma unroll
      for (int e = 0; e < E_NUM; ++e) if (e != i1 && acc[e] > acc[i2]) i2 = e;
      const float e2 = __expf(acc[i2] - acc[i1]);
      const float inv = 1.f / (1.f + e2);
      eid[t * 2] = i1;     wgt[t * 2] = inv;
      eid[t * 2 + 1] = i2; wgt[t * 2 + 1] = e2 * inv;
      atomicAdd(&s_cnt[i1], 1);
      atomicAdd(&s_cnt[i2], 1);
    }
  }
  __syncthreads();
  if (th < E_NUM && s_cnt[th] > 0) atomicAdd(&counts[th], s_cnt[th]);
}

// ---------------- scatter: block-local histogram + range reservation -------
__global__ void scatter_kernel(const int* __restrict__ eid, const int* __restrict__ counts,
                               int* __restrict__ fill, int* __restrict__ rowmap) {
  __shared__ int hist[E_NUM], base[E_NUM];
  const int th = threadIdx.x;
  const int p = blockIdx.x * 256 + th;
  if (th < E_NUM) hist[th] = 0;
  __syncthreads();
  const int e = eid[p];
  const int rloc = atomicAdd(&hist[e], 1);
  __syncthreads();
  if (th < E_NUM) base[th] = (hist[th] > 0) ? atomicAdd(&fill[th], hist[th]) : 0;
  __syncthreads();
  int off = 0;
#pragma unroll
  for (int i = 0; i < E_NUM; ++i) off += (i < e) ? counts[i] : 0;
  rowmap[off + base[e] + rloc] = p;
}

// ---------------- grouped GEMM: R6 structure + single-barrier 2-phase dbuf -
// MODE 0: A = gathered hs bf16, B = w1t [E][I][H] bf16, C = silu -> act bf16
// MODE 1: A = act bf16, B = w2t [E][H][I] bf16, C -> atomicAdd out * wgt
template <int MODE, int NCT>
__launch_bounds__(256, 2)
__global__ void moe_gemm(const unsigned short* __restrict__ hsb,
                         const unsigned short* __restrict__ wt,
                         const unsigned short* __restrict__ act_in,
                         unsigned short* __restrict__ act_out,
                         float* __restrict__ out,
                         const int* __restrict__ counts,
                         const int* __restrict__ rowmap,
                         const float* __restrict__ wgt) {
  constexpr int KD = (MODE == 0) ? H_DIM : I_DIM;
  constexpr int NT = KD / BK;
  constexpr int NWG = MAX_RT * NCT;    // %8 == 0 for both modes

  __shared__ unsigned short As[2][BM * BK];
  __shared__ unsigned short Bs[2][BN * BK];
  __shared__ int s_pair[BM];
  __shared__ float s_w[BM];

  // T1 bijective XCD swizzle, ct FAST within chunk: A-tile stays L2-resident
  const int bid = blockIdx.x;
  const int wgid = (bid & 7) * (NWG / 8) + (bid >> 3);
  const int rt = wgid / NCT;
  const int ct = wgid % NCT;

  // expert walk from counts (prefix on the fly)
  int e = -1, loc_rt = 0, off_e = 0, cnt = 0;
  {
    int acc_t = 0, off = 0;
#pragma unroll
    for (int ee = 0; ee < E_NUM; ++ee) {
      const int c = counts[ee];
      const int nt = (c + BM - 1) >> 7;
      if (e < 0 && rt < acc_t + nt) { e = ee; loc_rt = rt - acc_t; off_e = off; cnt = c; }
      acc_t += nt; off += c;
    }
  }
  if (e < 0) return;

  const int cnt_local = min(BM, cnt - loc_rt * BM);
  const int r_base = off_e + loc_rt * BM;
  const int th = threadIdx.x;
  const int lane = th & 63, wid = th >> 6;

  if (MODE == 1 && th < BM) {
    int r = loc_rt * BM + th;
    if (r >= cnt) r = cnt - 1;
    const int p = rowmap[off_e + r];
    s_pair[th] = p;
    s_w[th] = wgt[p];
  }

  const int n0 = ct * BN;
  const unsigned short* wbase = wt + (size_t)e * ((size_t)I_DIM * H_DIM) + (size_t)n0 * KD;

  // staging geometry: lane covers (row = i*32 + wid*8 + lane/8, chunk = lane%8)
  // LDS dest linear; source chunk pre-swizzled: cg = (lane&7) ^ (row&7)
  const int srow = lane >> 3;
  const int cg = (lane & 7) ^ srow;
  const char* aptr[4];
  const char* bptr[4];
#pragma unroll
  for (int i = 0; i < 4; ++i) {
    const int r = i * 32 + wid * 8 + srow;
    const int rr = (r < cnt_local) ? r : (cnt_local - 1);
    if (MODE == 0) {
      const int tok = rowmap[off_e + loc_rt * BM + rr] >> 1;
      aptr[i] = (const char*)(hsb + (size_t)tok * H_DIM) + cg * 16;
    } else {
      aptr[i] = (const char*)(act_in + (size_t)(r_base + rr) * I_DIM) + cg * 16;
    }
    bptr[i] = (const char*)(wbase + (size_t)r * KD) + cg * 16;
  }
  const int dso = (wid * 8) * BK;   // wave-uniform LDS row base (per i: +32*BK)

#define STAGE(buf, kb) do {                                               \
    _Pragma("unroll") for (int i = 0; i < 4; ++i)                         \
        gload16(aptr[i] + (kb), &As[buf][dso + i * 32 * BK]);             \
    _Pragma("unroll") for (int i = 0; i < 4; ++i)                         \
        gload16(bptr[i] + (kb), &Bs[buf][dso + i * 32 * BK]);             \
  } while (0)

  f32x4 acc[4][4];
#pragma unroll
  for (int m = 0; m < 4; ++m)
#pragma unroll
    for (int n = 0; n < 4; ++n) acc[m][n] = (f32x4){0.f, 0.f, 0.f, 0.f};

  const int wm = (wid >> 1) * 64;
  const int wn = (wid & 1) * 64;
  const int fr = lane & 15;
  const int fq = lane >> 4;
  const int sxor = fr & 7;

  // ---- prologue: stage tile 0, publish
  STAGE(0, 0);
  asm volatile("s_waitcnt vmcnt(0)" ::: "memory");
  __builtin_amdgcn_s_barrier();

  int cur = 0;
  for (int t = 0; t < NT; ++t) {
    // issue next tile's loads FIRST (in flight across ds_read + MFMA)
    if (t + 1 < NT) STAGE(cur ^ 1, (size_t)(t + 1) * BK * 2);
    __builtin_amdgcn_sched_barrier(0);

    // ds_read all fragments of tile t
    bf16x8 af[4][2], bfq[4][2];
#pragma unroll
    for (int m = 0; m < 4; ++m)
#pragma unroll
      for (int kk = 0; kk < 2; ++kk)
        af[m][kk] = *reinterpret_cast<const bf16x8*>(
            &As[cur][(wm + m * 16 + fr) * BK + ((kk * 4 + fq) ^ sxor) * 8]);
#pragma unroll
    for (int n = 0; n < 4; ++n)
#pragma unroll
      for (int kk = 0; kk < 2; ++kk)
        bfq[n][kk] = *reinterpret_cast<const bf16x8*>(
            &Bs[cur][(wn + n * 16 + fr) * BK + ((kk * 4 + fq) ^ sxor) * 8]);
    asm volatile("s_waitcnt lgkmcnt(0)" ::: "memory");
    __builtin_amdgcn_sched_barrier(0);

    __builtin_amdgcn_s_setprio(1);
#pragma unroll
    for (int kk = 0; kk < 2; ++kk)
#pragma unroll
      for (int m = 0; m < 4; ++m)
#pragma unroll
        for (int n = 0; n < 4; ++n)
          acc[m][n] = __builtin_amdgcn_mfma_f32_16x16x32_bf16(af[m][kk], bfq[n][kk], acc[m][n], 0, 0, 0);
    __builtin_amdgcn_s_setprio(0);

    // single barrier per K-step: next tile landed, this tile's readers done
    if (t + 1 < NT) {
      asm volatile("s_waitcnt vmcnt(0)" ::: "memory");
      __builtin_amdgcn_sched_barrier(0);
      __builtin_amdgcn_s_barrier();
    }
    cur ^= 1;
  }
#undef STAGE

  // ---- epilogue ----
#pragma unroll
  for (int m = 0; m < 4; ++m) {
    const int row = wm + m * 16 + fq * 4;
#pragma unroll
    for (int n = 0; n < 4; ++n) {
      const int col = wn + n * 16 + fr;
#pragma unroll
      for (int r = 0; r < 4; ++r) {
        const int rw = row + r;
        if (rw < cnt_local) {
          const float x = acc[m][n][r];
          if (MODE == 0) {
            const float s = x / (1.f + __expf(-x));   // silu
            act_out[(size_t)(r_base + rw) * I_DIM + n0 + col] = f2bf(s);
          } else {
            const int p = s_pair[rw];
            const int tok = p >> 1;
            atomicAdd(out + (size_t)tok * H_DIM + n0 + col, x * s_w[rw]);
          }
        }
      }
    }
  }
}

// ---------------- launch ----------------
extern "C" void kernel_launch(void* const* d_in, const int* in_sizes, int n_in,
                              void* d_out, int out_size, void* d_ws, size_t ws_size,
                              hipStream_t stream) {
  const float* hs = (const float*)d_in[0];
  const float* gw = (const float*)d_in[1];
  const float* w1 = (const float*)d_in[2];
  const float* w2 = (const float*)d_in[3];
  float* out = (float*)d_out;

  char* ws = (char*)d_ws;
  const size_t WMAT = (size_t)E_NUM * I_DIM * H_DIM * 2;   // 58,720,256 B
  unsigned short* w1t = (unsigned short*)ws;                // [E][I][H] bf16
  unsigned short* w2t = (unsigned short*)(ws + WMAT);       // [E][H][I] bf16
  unsigned short* act = (unsigned short*)(ws + 2 * WMAT);   // [NPAIR][I] bf16
  unsigned short* hsb = (unsigned short*)(ws + 3 * WMAT);   // [T][H] bf16
  char* small = ws + 3 * WMAT + (size_t)T_TOK * H_DIM * 2;
  int* eid = (int*)small;                          // NPAIR
  float* wgt = (float*)(small + NPAIR * 4);        // NPAIR
  int* rowmap = (int*)(small + 2 * NPAIR * 4);     // NPAIR
  int* counts = (int*)(small + 3 * NPAIR * 4);     // 8
  int* fill = counts + 8;                          // 8

  hipMemsetAsync(d_out, 0, (size_t)T_TOK * H_DIM * sizeof(float), stream);
  hipMemsetAsync(counts, 0, 16 * sizeof(int), stream);

  transpose_cvt<<<dim3(I_DIM / 64, H_DIM / 64, E_NUM), 256, 0, stream>>>(w1, w1t, H_DIM, I_DIM);
  transpose_cvt<<<dim3(H_DIM / 64, I_DIM / 64, E_NUM), 256, 0, stream>>>(w2, w2t, I_DIM, H_DIM);

  router_kernel<<<T_TOK / 16, 256, 0, stream>>>(hs, gw, hsb, eid, wgt, counts);
  scatter_kernel<<<NPAIR / 256, 256, 0, stream>>>(eid, counts, fill, rowmap);

  moe_gemm<0, I_DIM / BN><<<MAX_RT * (I_DIM / BN), 256, 0, stream>>>(
      hsb, w1t, nullptr, act, nullptr, counts, rowmap, wgt);
  moe_gemm<1, H_DIM / BN><<<MAX_RT * (H_DIM / BN), 256, 0, stream>>>(
      hsb, w2t, act, nullptr, out, counts, rowmap, wgt);
}

// Round 9
// 309.704 us; speedup vs baseline: 1.1992x; 1.1310x over previous
//
#include <hip/hip_runtime.h>
#include <hip/hip_bf16.h>

// ---------------- problem constants (match setup_inputs) ----------------
#define T_TOK 4096
#define H_DIM 1024
#define E_NUM 8
#define I_DIM 3584
#define NPAIR (T_TOK * 2)   // top_k = 2
#define MAX_RT 72           // worst-case total row tiles: sum ceil(cnt_e/128) <= 64+7

#define BM 128
#define BN 128
#define BK 64

typedef __attribute__((ext_vector_type(8))) short bf16x8;
typedef __attribute__((ext_vector_type(4))) float f32x4;
typedef __attribute__((ext_vector_type(8))) unsigned short ushort8_t;
typedef __attribute__((ext_vector_type(4))) unsigned short ushort4_t;

// RNE fp32 -> bf16
__device__ __forceinline__ unsigned short f2bf(float x) {
  unsigned int u = __float_as_uint(x);
  unsigned int r = (u + 0x7FFFu + ((u >> 16) & 1u)) >> 16;
  return (unsigned short)r;
}

// async 16B global -> LDS (dest: wave-uniform base, HW adds lane*16)
__device__ __forceinline__ void gload16(const void* g, unsigned short* l) {
  __builtin_amdgcn_global_load_lds(
      (const __attribute__((address_space(1))) void*)g,
      (__attribute__((address_space(3))) void*)l, 16, 0, 0);
}

// ---------------- transpose + fp32->bf16 convert ----------------
__global__ void transpose_cvt(const float* __restrict__ src,
                              unsigned short* __restrict__ dst, int R, int C) {
  __shared__ float tile[64][65];
  const int e = blockIdx.z;
  const int c0 = blockIdx.x * 64, r0 = blockIdx.y * 64;
  const float* s = src + (size_t)e * R * C;
  unsigned short* d = dst + (size_t)e * R * C;
  const int th = threadIdx.x;
  const int tr = th >> 4;
  const int tc4 = (th & 15) * 4;
#pragma unroll
  for (int it = 0; it < 4; ++it) {
    const int r = it * 16 + tr;
    float4 v = *reinterpret_cast<const float4*>(s + (size_t)(r0 + r) * C + c0 + tc4);
    tile[r][tc4] = v.x; tile[r][tc4 + 1] = v.y; tile[r][tc4 + 2] = v.z; tile[r][tc4 + 3] = v.w;
  }
  __syncthreads();
  const int wc = th >> 3;
  const int wr = (th & 7) * 8;
#pragma unroll
  for (int it = 0; it < 2; ++it) {
    const int c = it * 32 + wc;
    ushort8_t o;
#pragma unroll
    for (int j = 0; j < 8; ++j) o[j] = f2bf(tile[wr + j][c]);
    *reinterpret_cast<ushort8_t*>(d + (size_t)(c0 + c) * R + r0 + wr) = o;
  }
}

// ---------------- router: LDS-staged gw, float4 hs, LDS-aggregated counts --
__global__ void router_kernel(const float* __restrict__ hs, const float* __restrict__ gw,
                              unsigned short* __restrict__ hsb,
                              int* __restrict__ eid, float* __restrict__ wgt,
                              int* __restrict__ counts) {
  __shared__ float s_gw[8192];
  __shared__ int s_cnt[E_NUM];
  const int th = threadIdx.x;
  for (int u = th; u < 2048; u += 256) {
    const f32x4 v = *reinterpret_cast<const f32x4*>(gw + u * 4);
    *reinterpret_cast<f32x4*>(&s_gw[(u ^ ((u >> 3) & 7)) * 4]) = v;
  }
  if (th < E_NUM) s_cnt[th] = 0;
  __syncthreads();

  const int l = th & 63, w = th >> 6;
#pragma unroll 1
  for (int tt = 0; tt < 4; ++tt) {
    const int t = blockIdx.x * 16 + w * 4 + tt;
    const float* hrow = hs + (size_t)t * H_DIM;
    unsigned short* brow = hsb + (size_t)t * H_DIM;
    float acc[E_NUM];
#pragma unroll
    for (int e = 0; e < E_NUM; ++e) acc[e] = 0.f;
#pragma unroll
    for (int i = 0; i < 4; ++i) {
      const int h0 = i * 256 + l * 4;
      const f32x4 x = *reinterpret_cast<const f32x4*>(hrow + h0);
      ushort4_t o = { f2bf(x[0]), f2bf(x[1]), f2bf(x[2]), f2bf(x[3]) };
      *reinterpret_cast<ushort4_t*>(brow + h0) = o;
#pragma unroll
      for (int j = 0; j < 4; ++j) {
        const int h = h0 + j;
        const int p0 = (h * 2) ^ ((h >> 2) & 7);
        const f32x4 g0 = *reinterpret_cast<const f32x4*>(&s_gw[p0 * 4]);
        const f32x4 g1 = *reinterpret_cast<const f32x4*>(&s_gw[(p0 ^ 1) * 4]);
        acc[0] += x[j] * g0[0]; acc[1] += x[j] * g0[1];
        acc[2] += x[j] * g0[2]; acc[3] += x[j] * g0[3];
        acc[4] += x[j] * g1[0]; acc[5] += x[j] * g1[1];
        acc[6] += x[j] * g1[2]; acc[7] += x[j] * g1[3];
      }
    }
#pragma unroll
    for (int e = 0; e < E_NUM; ++e) {
#pragma unroll
      for (int off = 1; off < 64; off <<= 1) acc[e] += __shfl_xor(acc[e], off);
    }
    if (l == 0) {
      int i1 = 0;
#pragma unroll
      for (int e = 1; e < E_NUM; ++e) if (acc[e] > acc[i1]) i1 = e;
      int i2 = (i1 == 0) ? 1 : 0;
#pragma unroll
      for (int e = 0; e < E_NUM; ++e) if (e != i1 && acc[e] > acc[i2]) i2 = e;
      const float e2 = __expf(acc[i2] - acc[i1]);
      const float inv = 1.f / (1.f + e2);
      eid[t * 2] = i1;     wgt[t * 2] = inv;
      eid[t * 2 + 1] = i2; wgt[t * 2 + 1] = e2 * inv;
      atomicAdd(&s_cnt[i1], 1);
      atomicAdd(&s_cnt[i2], 1);
    }
  }
  __syncthreads();
  if (th < E_NUM && s_cnt[th] > 0) atomicAdd(&counts[th], s_cnt[th]);
}

// ---------------- scatter: block-local histogram + range reservation -------
__global__ void scatter_kernel(const int* __restrict__ eid, const int* __restrict__ counts,
                               int* __restrict__ fill, int* __restrict__ rowmap) {
  __shared__ int hist[E_NUM], base[E_NUM];
  const int th = threadIdx.x;
  const int p = blockIdx.x * 256 + th;
  if (th < E_NUM) hist[th] = 0;
  __syncthreads();
  const int e = eid[p];
  const int rloc = atomicAdd(&hist[e], 1);
  __syncthreads();
  if (th < E_NUM) base[th] = (hist[th] > 0) ? atomicAdd(&fill[th], hist[th]) : 0;
  __syncthreads();
  int off = 0;
#pragma unroll
  for (int i = 0; i < E_NUM; ++i) off += (i < e) ? counts[i] : 0;
  rowmap[off + base[e] + rloc] = p;
}

// ---------------- grouped GEMM (R6 structure + supertile / K-split) --------
// MODE 0: A = gathered hs bf16 (K=1024), B = w1t [E][I][H], C = silu -> act
// MODE 1: A = act bf16 (K-split KS x 1792), B = w2t [E][H][I], C -> atomicAdd
template <int MODE, int NCT, int KS>
__launch_bounds__(256, 4)
__global__ void moe_gemm(const unsigned short* __restrict__ hsb,
                         const unsigned short* __restrict__ wt,
                         const unsigned short* __restrict__ act_in,
                         unsigned short* __restrict__ act_out,
                         float* __restrict__ out,
                         const int* __restrict__ counts,
                         const int* __restrict__ rowmap,
                         const float* __restrict__ wgt) {
  constexpr int KROW = (MODE == 0) ? H_DIM : I_DIM;   // row stride of A/B
  constexpr int KD = KROW / KS;                        // K extent per block
  constexpr int NT = KD / BK;
  constexpr int NWG = MAX_RT * NCT * KS;               // 2016 / 1152, %8==0

  __shared__ unsigned short As[BM * BK];
  __shared__ unsigned short Bs[BN * BK];
  __shared__ int s_pair[BM];
  __shared__ float s_w[BM];

  // T1 bijective XCD swizzle
  const int bid = blockIdx.x;
  const int wgid = (bid & 7) * (NWG / 8) + (bid >> 3);
  int rt, ct, kbase;
  if (MODE == 0) {
    // chunk = 9 rt x 28 ct (NWG/8 = 252); supertile 9rt x 4ct:
    // A window 2.25MB + B window 1MB both L2-resident per XCD.
    const int l = wgid % 252;
    const int cb = (wgid / 252) * 9;
    const int q = l % 36;
    rt = cb + q % 9;
    ct = (l / 36) * 4 + q / 9;
    kbase = 0;
  } else {
    // rt slow (A seg L2-resident across all 16 (ct,ks) columns)
    rt = wgid / (NCT * KS);
    const int col = wgid % (NCT * KS);
    ct = col % NCT;
    kbase = (col / NCT) * KD;
  }

  // expert walk from counts (prefix on the fly)
  int e = -1, loc_rt = 0, off_e = 0, cnt = 0;
  {
    int acc_t = 0, off = 0;
#pragma unroll
    for (int ee = 0; ee < E_NUM; ++ee) {
      const int c = counts[ee];
      const int nt = (c + BM - 1) >> 7;
      if (e < 0 && rt < acc_t + nt) { e = ee; loc_rt = rt - acc_t; off_e = off; cnt = c; }
      acc_t += nt; off += c;
    }
  }
  if (e < 0) return;

  const int cnt_local = min(BM, cnt - loc_rt * BM);
  const int r_base = off_e + loc_rt * BM;
  const int th = threadIdx.x;
  const int lane = th & 63, wid = th >> 6;

  if (MODE == 1 && th < BM) {
    int r = loc_rt * BM + th;
    if (r >= cnt) r = cnt - 1;
    const int p = rowmap[off_e + r];
    s_pair[th] = p;
    s_w[th] = wgt[p];
  }

  const int n0 = ct * BN;
  const unsigned short* wbase =
      wt + (size_t)e * ((size_t)I_DIM * H_DIM) + (size_t)n0 * KROW + kbase;

  // staging geometry: lane covers (row = i*32 + wid*8 + lane/8, chunk = lane%8)
  // LDS dest linear; source chunk pre-swizzled: cg = (lane&7) ^ (row&7)
  const int srow = lane >> 3;
  const int cg = (lane & 7) ^ srow;
  const char* aptr[4];
  const char* bptr[4];
#pragma unroll
  for (int i = 0; i < 4; ++i) {
    const int r = i * 32 + wid * 8 + srow;
    const int rr = (r < cnt_local) ? r : (cnt_local - 1);
    if (MODE == 0) {
      const int tok = rowmap[off_e + loc_rt * BM + rr] >> 1;
      aptr[i] = (const char*)(hsb + (size_t)tok * H_DIM) + cg * 16;
    } else {
      aptr[i] = (const char*)(act_in + (size_t)(r_base + rr) * I_DIM + kbase) + cg * 16;
    }
    bptr[i] = (const char*)(wbase + (size_t)r * KROW) + cg * 16;
  }
  unsigned short* dstA[4];
  unsigned short* dstB[4];
#pragma unroll
  for (int i = 0; i < 4; ++i) {
    dstA[i] = &As[(i * 32 + wid * 8) * BK];   // wave-uniform
    dstB[i] = &Bs[(i * 32 + wid * 8) * BK];
  }

  f32x4 acc[4][4];
#pragma unroll
  for (int m = 0; m < 4; ++m)
#pragma unroll
    for (int n = 0; n < 4; ++n) acc[m][n] = (f32x4){0.f, 0.f, 0.f, 0.f};

  const int wm = (wid >> 1) * 64;
  const int wn = (wid & 1) * 64;
  const int fr = lane & 15;
  const int fq = lane >> 4;
  const int sxor = fr & 7;

  for (int k0 = 0; k0 < KD; k0 += BK) {
    const int kb = k0 * 2;
#pragma unroll
    for (int i = 0; i < 4; ++i) gload16(aptr[i] + kb, dstA[i]);
#pragma unroll
    for (int i = 0; i < 4; ++i) gload16(bptr[i] + kb, dstB[i]);
    __syncthreads();   // drains vmcnt before s_barrier

#pragma unroll
    for (int kk = 0; kk < 2; ++kk) {
      bf16x8 af[4], bf[4];
#pragma unroll
      for (int m = 0; m < 4; ++m)
        af[m] = *reinterpret_cast<const bf16x8*>(
            &As[(wm + m * 16 + fr) * BK + ((kk * 4 + fq) ^ sxor) * 8]);
#pragma unroll
      for (int n = 0; n < 4; ++n)
        bf[n] = *reinterpret_cast<const bf16x8*>(
            &Bs[(wn + n * 16 + fr) * BK + ((kk * 4 + fq) ^ sxor) * 8]);
#pragma unroll
      for (int m = 0; m < 4; ++m)
#pragma unroll
        for (int n = 0; n < 4; ++n)
          acc[m][n] = __builtin_amdgcn_mfma_f32_16x16x32_bf16(af[m], bf[n], acc[m][n], 0, 0, 0);
    }
    __syncthreads();
  }

  // ---- epilogue ----
#pragma unroll
  for (int m = 0; m < 4; ++m) {
    const int row = wm + m * 16 + fq * 4;
#pragma unroll
    for (int n = 0; n < 4; ++n) {
      const int col = wn + n * 16 + fr;
#pragma unroll
      for (int r = 0; r < 4; ++r) {
        const int rw = row + r;
        if (rw < cnt_local) {
          const float x = acc[m][n][r];
          if (MODE == 0) {
            const float s = x / (1.f + __expf(-x));   // silu
            act_out[(size_t)(r_base + rw) * I_DIM + n0 + col] = f2bf(s);
          } else {
            const int p = s_pair[rw];
            const int tok = p >> 1;
            atomicAdd(out + (size_t)tok * H_DIM + n0 + col, x * s_w[rw]);
          }
        }
      }
    }
  }
}

// ---------------- launch ----------------
extern "C" void kernel_launch(void* const* d_in, const int* in_sizes, int n_in,
                              void* d_out, int out_size, void* d_ws, size_t ws_size,
                              hipStream_t stream) {
  const float* hs = (const float*)d_in[0];
  const float* gw = (const float*)d_in[1];
  const float* w1 = (const float*)d_in[2];
  const float* w2 = (const float*)d_in[3];
  float* out = (float*)d_out;

  char* ws = (char*)d_ws;
  const size_t WMAT = (size_t)E_NUM * I_DIM * H_DIM * 2;   // 58,720,256 B
  unsigned short* w1t = (unsigned short*)ws;                // [E][I][H] bf16
  unsigned short* w2t = (unsigned short*)(ws + WMAT);       // [E][H][I] bf16
  unsigned short* act = (unsigned short*)(ws + 2 * WMAT);   // [NPAIR][I] bf16
  unsigned short* hsb = (unsigned short*)(ws + 3 * WMAT);   // [T][H] bf16
  char* small = ws + 3 * WMAT + (size_t)T_TOK * H_DIM * 2;
  int* eid = (int*)small;                          // NPAIR
  float* wgt = (float*)(small + NPAIR * 4);        // NPAIR
  int* rowmap = (int*)(small + 2 * NPAIR * 4);     // NPAIR
  int* counts = (int*)(small + 3 * NPAIR * 4);     // 8
  int* fill = counts + 8;                          // 8

  hipMemsetAsync(d_out, 0, (size_t)T_TOK * H_DIM * sizeof(float), stream);
  hipMemsetAsync(counts, 0, 16 * sizeof(int), stream);

  transpose_cvt<<<dim3(I_DIM / 64, H_DIM / 64, E_NUM), 256, 0, stream>>>(w1, w1t, H_DIM, I_DIM);
  transpose_cvt<<<dim3(H_DIM / 64, I_DIM / 64, E_NUM), 256, 0, stream>>>(w2, w2t, I_DIM, H_DIM);

  router_kernel<<<T_TOK / 16, 256, 0, stream>>>(hs, gw, hsb, eid, wgt, counts);
  scatter_kernel<<<NPAIR / 256, 256, 0, stream>>>(eid, counts, fill, rowmap);

  // MODE0: 72 rt x 28 ct, K=1024
  moe_gemm<0, I_DIM / BN, 1><<<MAX_RT * (I_DIM / BN), 256, 0, stream>>>(
      hsb, w1t, nullptr, act, nullptr, counts, rowmap, wgt);
  // MODE1: 72 rt x 8 ct x KS=2 (K-split 1792 each), atomic output
  moe_gemm<1, H_DIM / BN, 2><<<MAX_RT * (H_DIM / BN) * 2, 256, 0, stream>>>(
      hsb, w2t, act, nullptr, out, counts, rowmap, wgt);
}

// Round 10
// 286.266 us; speedup vs baseline: 1.2974x; 1.0819x over previous
//
#include <hip/hip_runtime.h>
#include <hip/hip_bf16.h>

// ---------------- problem constants (match setup_inputs) ----------------
#define T_TOK 4096
#define H_DIM 1024
#define E_NUM 8
#define I_DIM 3584
#define NPAIR (T_TOK * 2)   // top_k = 2
#define MAX_RT 72           // worst-case total row tiles: sum ceil(cnt_e/128) <= 64+7

#define BM 128
#define BN 128
#define BK 64

typedef __attribute__((ext_vector_type(8))) short bf16x8;
typedef __attribute__((ext_vector_type(4))) float f32x4;
typedef __attribute__((ext_vector_type(8))) unsigned short ushort8_t;
typedef __attribute__((ext_vector_type(4))) unsigned short ushort4_t;

// RNE fp32 -> bf16
__device__ __forceinline__ unsigned short f2bf(float x) {
  unsigned int u = __float_as_uint(x);
  unsigned int r = (u + 0x7FFFu + ((u >> 16) & 1u)) >> 16;
  return (unsigned short)r;
}

// async 16B global -> LDS (dest: wave-uniform base, HW adds lane*16)
__device__ __forceinline__ void gload16(const void* g, unsigned short* l) {
  __builtin_amdgcn_global_load_lds(
      (const __attribute__((address_space(1))) void*)g,
      (__attribute__((address_space(3))) void*)l, 16, 0, 0);
}

// ---------------- transpose + fp32->bf16 convert ----------------
__global__ void transpose_cvt(const float* __restrict__ src,
                              unsigned short* __restrict__ dst, int R, int C) {
  __shared__ float tile[64][65];
  const int e = blockIdx.z;
  const int c0 = blockIdx.x * 64, r0 = blockIdx.y * 64;
  const float* s = src + (size_t)e * R * C;
  unsigned short* d = dst + (size_t)e * R * C;
  const int th = threadIdx.x;
  const int tr = th >> 4;
  const int tc4 = (th & 15) * 4;
#pragma unroll
  for (int it = 0; it < 4; ++it) {
    const int r = it * 16 + tr;
    float4 v = *reinterpret_cast<const float4*>(s + (size_t)(r0 + r) * C + c0 + tc4);
    tile[r][tc4] = v.x; tile[r][tc4 + 1] = v.y; tile[r][tc4 + 2] = v.z; tile[r][tc4 + 3] = v.w;
  }
  __syncthreads();
  const int wc = th >> 3;
  const int wr = (th & 7) * 8;
#pragma unroll
  for (int it = 0; it < 2; ++it) {
    const int c = it * 32 + wc;
    ushort8_t o;
#pragma unroll
    for (int j = 0; j < 8; ++j) o[j] = f2bf(tile[wr + j][c]);
    *reinterpret_cast<ushort8_t*>(d + (size_t)(c0 + c) * R + r0 + wr) = o;
  }
}

// ---------------- router: LDS-staged gw, float4 hs, LDS-aggregated counts --
__global__ void router_kernel(const float* __restrict__ hs, const float* __restrict__ gw,
                              unsigned short* __restrict__ hsb,
                              int* __restrict__ eid, float* __restrict__ wgt,
                              int* __restrict__ counts) {
  __shared__ float s_gw[8192];
  __shared__ int s_cnt[E_NUM];
  const int th = threadIdx.x;
  for (int u = th; u < 2048; u += 256) {
    const f32x4 v = *reinterpret_cast<const f32x4*>(gw + u * 4);
    *reinterpret_cast<f32x4*>(&s_gw[(u ^ ((u >> 3) & 7)) * 4]) = v;
  }
  if (th < E_NUM) s_cnt[th] = 0;
  __syncthreads();

  const int l = th & 63, w = th >> 6;
#pragma unroll 1
  for (int tt = 0; tt < 4; ++tt) {
    const int t = blockIdx.x * 16 + w * 4 + tt;
    const float* hrow = hs + (size_t)t * H_DIM;
    unsigned short* brow = hsb + (size_t)t * H_DIM;
    float acc[E_NUM];
#pragma unroll
    for (int e = 0; e < E_NUM; ++e) acc[e] = 0.f;
#pragma unroll
    for (int i = 0; i < 4; ++i) {
      const int h0 = i * 256 + l * 4;
      const f32x4 x = *reinterpret_cast<const f32x4*>(hrow + h0);
      ushort4_t o = { f2bf(x[0]), f2bf(x[1]), f2bf(x[2]), f2bf(x[3]) };
      *reinterpret_cast<ushort4_t*>(brow + h0) = o;
#pragma unroll
      for (int j = 0; j < 4; ++j) {
        const int h = h0 + j;
        const int p0 = (h * 2) ^ ((h >> 2) & 7);
        const f32x4 g0 = *reinterpret_cast<const f32x4*>(&s_gw[p0 * 4]);
        const f32x4 g1 = *reinterpret_cast<const f32x4*>(&s_gw[(p0 ^ 1) * 4]);
        acc[0] += x[j] * g0[0]; acc[1] += x[j] * g0[1];
        acc[2] += x[j] * g0[2]; acc[3] += x[j] * g0[3];
        acc[4] += x[j] * g1[0]; acc[5] += x[j] * g1[1];
        acc[6] += x[j] * g1[2]; acc[7] += x[j] * g1[3];
      }
    }
#pragma unroll
    for (int e = 0; e < E_NUM; ++e) {
#pragma unroll
      for (int off = 1; off < 64; off <<= 1) acc[e] += __shfl_xor(acc[e], off);
    }
    if (l == 0) {
      int i1 = 0;
#pragma unroll
      for (int e = 1; e < E_NUM; ++e) if (acc[e] > acc[i1]) i1 = e;
      int i2 = (i1 == 0) ? 1 : 0;
#pragma unroll
      for (int e = 0; e < E_NUM; ++e) if (e != i1 && acc[e] > acc[i2]) i2 = e;
      const float e2 = __expf(acc[i2] - acc[i1]);
      const float inv = 1.f / (1.f + e2);
      eid[t * 2] = i1;     wgt[t * 2] = inv;
      eid[t * 2 + 1] = i2; wgt[t * 2 + 1] = e2 * inv;
      atomicAdd(&s_cnt[i1], 1);
      atomicAdd(&s_cnt[i2], 1);
    }
  }
  __syncthreads();
  if (th < E_NUM && s_cnt[th] > 0) atomicAdd(&counts[th], s_cnt[th]);
}

// ---------------- scatter: block-local histogram + range reservation -------
// also records posmap: pair -> sorted row position (for atomic-free combine)
__global__ void scatter_kernel(const int* __restrict__ eid, const int* __restrict__ counts,
                               int* __restrict__ fill, int* __restrict__ rowmap,
                               int* __restrict__ posmap) {
  __shared__ int hist[E_NUM], base[E_NUM];
  const int th = threadIdx.x;
  const int p = blockIdx.x * 256 + th;
  if (th < E_NUM) hist[th] = 0;
  __syncthreads();
  const int e = eid[p];
  const int rloc = atomicAdd(&hist[e], 1);
  __syncthreads();
  if (th < E_NUM) base[th] = (hist[th] > 0) ? atomicAdd(&fill[th], hist[th]) : 0;
  __syncthreads();
  int off = 0;
#pragma unroll
  for (int i = 0; i < E_NUM; ++i) off += (i < e) ? counts[i] : 0;
  const int pos = off + base[e] + rloc;
  rowmap[pos] = p;
  posmap[p] = pos;
}

// ---------------- combine: out[t] = res[pos(2t)] + res[pos(2t+1)] ----------
__global__ void combine_kernel(const float* __restrict__ res, const int* __restrict__ posmap,
                               float* __restrict__ out) {
  const int t = blockIdx.x;
  const int th = threadIdx.x;
  const int a = posmap[t * 2];
  const int b = posmap[t * 2 + 1];
  const float4 va = *reinterpret_cast<const float4*>(res + (size_t)a * H_DIM + th * 4);
  const float4 vb = *reinterpret_cast<const float4*>(res + (size_t)b * H_DIM + th * 4);
  float4 o = { va.x + vb.x, va.y + vb.y, va.z + vb.z, va.w + vb.w };
  *reinterpret_cast<float4*>(out + (size_t)t * H_DIM + th * 4) = o;
}

// ---------------- grouped GEMM (R6 structure; ct-fast XCD swizzle) ---------
// MODE 0: A = gathered hs bf16, B = w1t [E][I][H] bf16, C = silu -> act bf16
// MODE 1: A = act bf16, B = w2t [E][H][I] bf16, C = x*w -> res (plain stores)
template <int MODE, int NCT>
__launch_bounds__(256, 4)
__global__ void moe_gemm(const unsigned short* __restrict__ hsb,
                         const unsigned short* __restrict__ wt,
                         const unsigned short* __restrict__ act_in,
                         unsigned short* __restrict__ act_out,
                         float* __restrict__ res,
                         const int* __restrict__ counts,
                         const int* __restrict__ rowmap,
                         const float* __restrict__ wgt) {
  constexpr int KD = (MODE == 0) ? H_DIM : I_DIM;
  constexpr int NWG = MAX_RT * NCT;    // %8 == 0 for both modes

  __shared__ unsigned short As[BM * BK];
  __shared__ unsigned short Bs[BN * BK];
  __shared__ float s_w[BM];

  // T1 bijective XCD swizzle, ct FAST within chunk: A-tile stays L2-resident
  const int bid = blockIdx.x;
  const int wgid = (bid & 7) * (NWG / 8) + (bid >> 3);
  const int rt = wgid / NCT;
  const int ct = wgid % NCT;

  // expert walk from counts (prefix on the fly)
  int e = -1, loc_rt = 0, off_e = 0, cnt = 0;
  {
    int acc_t = 0, off = 0;
#pragma unroll
    for (int ee = 0; ee < E_NUM; ++ee) {
      const int c = counts[ee];
      const int nt = (c + BM - 1) >> 7;
      if (e < 0 && rt < acc_t + nt) { e = ee; loc_rt = rt - acc_t; off_e = off; cnt = c; }
      acc_t += nt; off += c;
    }
  }
  if (e < 0) return;

  const int cnt_local = min(BM, cnt - loc_rt * BM);
  const int r_base = off_e + loc_rt * BM;
  const int th = threadIdx.x;
  const int lane = th & 63, wid = th >> 6;

  if (MODE == 1 && th < BM) {
    int r = loc_rt * BM + th;
    if (r >= cnt) r = cnt - 1;
    s_w[th] = wgt[rowmap[off_e + r]];
  }

  const int n0 = ct * BN;
  const unsigned short* wbase = wt + (size_t)e * ((size_t)I_DIM * H_DIM) + (size_t)n0 * KD;

  // staging geometry: lane covers (row = i*32 + wid*8 + lane/8, chunk = lane%8)
  // LDS dest linear; source chunk pre-swizzled: cg = (lane&7) ^ (row&7)
  const int srow = lane >> 3;
  const int cg = (lane & 7) ^ srow;
  const char* aptr[4];
  const char* bptr[4];
#pragma unroll
  for (int i = 0; i < 4; ++i) {
    const int r = i * 32 + wid * 8 + srow;
    const int rr = (r < cnt_local) ? r : (cnt_local - 1);
    if (MODE == 0) {
      const int tok = rowmap[off_e + loc_rt * BM + rr] >> 1;
      aptr[i] = (const char*)(hsb + (size_t)tok * H_DIM) + cg * 16;
    } else {
      aptr[i] = (const char*)(act_in + (size_t)(r_base + rr) * I_DIM) + cg * 16;
    }
    bptr[i] = (const char*)(wbase + (size_t)r * KD) + cg * 16;
  }
  unsigned short* dstA[4];
  unsigned short* dstB[4];
#pragma unroll
  for (int i = 0; i < 4; ++i) {
    dstA[i] = &As[(i * 32 + wid * 8) * BK];   // wave-uniform
    dstB[i] = &Bs[(i * 32 + wid * 8) * BK];
  }

  f32x4 acc[4][4];
#pragma unroll
  for (int m = 0; m < 4; ++m)
#pragma unroll
    for (int n = 0; n < 4; ++n) acc[m][n] = (f32x4){0.f, 0.f, 0.f, 0.f};

  const int wm = (wid >> 1) * 64;
  const int wn = (wid & 1) * 64;
  const int fr = lane & 15;
  const int fq = lane >> 4;
  const int sxor = fr & 7;

  for (int k0 = 0; k0 < KD; k0 += BK) {
    const int kb = k0 * 2;
#pragma unroll
    for (int i = 0; i < 4; ++i) gload16(aptr[i] + kb, dstA[i]);
#pragma unroll
    for (int i = 0; i < 4; ++i) gload16(bptr[i] + kb, dstB[i]);
    __syncthreads();   // drains vmcnt before s_barrier

#pragma unroll
    for (int kk = 0; kk < 2; ++kk) {
      bf16x8 af[4], bf[4];
#pragma unroll
      for (int m = 0; m < 4; ++m)
        af[m] = *reinterpret_cast<const bf16x8*>(
            &As[(wm + m * 16 + fr) * BK + ((kk * 4 + fq) ^ sxor) * 8]);
#pragma unroll
      for (int n = 0; n < 4; ++n)
        bf[n] = *reinterpret_cast<const bf16x8*>(
            &Bs[(wn + n * 16 + fr) * BK + ((kk * 4 + fq) ^ sxor) * 8]);
#pragma unroll
      for (int m = 0; m < 4; ++m)
#pragma unroll
        for (int n = 0; n < 4; ++n)
          acc[m][n] = __builtin_amdgcn_mfma_f32_16x16x32_bf16(af[m], bf[n], acc[m][n], 0, 0, 0);
    }
    __syncthreads();
  }

  // ---- epilogue ----
#pragma unroll
  for (int m = 0; m < 4; ++m) {
    const int row = wm + m * 16 + fq * 4;
#pragma unroll
    for (int n = 0; n < 4; ++n) {
      const int col = wn + n * 16 + fr;
#pragma unroll
      for (int r = 0; r < 4; ++r) {
        const int rw = row + r;
        if (rw < cnt_local) {
          const float x = acc[m][n][r];
          if (MODE == 0) {
            const float s = x / (1.f + __expf(-x));   // silu
            act_out[(size_t)(r_base + rw) * I_DIM + n0 + col] = f2bf(s);
          } else {
            res[(size_t)(r_base + rw) * H_DIM + n0 + col] = x * s_w[rw];
          }
        }
      }
    }
  }
}

// ---------------- launch ----------------
extern "C" void kernel_launch(void* const* d_in, const int* in_sizes, int n_in,
                              void* d_out, int out_size, void* d_ws, size_t ws_size,
                              hipStream_t stream) {
  const float* hs = (const float*)d_in[0];
  const float* gw = (const float*)d_in[1];
  const float* w1 = (const float*)d_in[2];
  const float* w2 = (const float*)d_in[3];
  float* out = (float*)d_out;

  char* ws = (char*)d_ws;
  const size_t WMAT = (size_t)E_NUM * I_DIM * H_DIM * 2;   // 58,720,256 B
  unsigned short* w1t = (unsigned short*)ws;                // [E][I][H] bf16
  unsigned short* w2t = (unsigned short*)(ws + WMAT);       // [E][H][I] bf16
  unsigned short* act = (unsigned short*)(ws + 2 * WMAT);   // [NPAIR][I] bf16
  unsigned short* hsb = (unsigned short*)(ws + 3 * WMAT);   // [T][H] bf16
  // res aliases w1t: dead after MODE0 completes (stream-ordered, race-free).
  float* res = (float*)w1t;                                 // [NPAIR][H] fp32 (32MB <= 58.7MB)
  char* small = ws + 3 * WMAT + (size_t)T_TOK * H_DIM * 2;
  int* eid = (int*)small;                          // NPAIR
  float* wgt = (float*)(small + NPAIR * 4);        // NPAIR
  int* rowmap = (int*)(small + 2 * NPAIR * 4);     // NPAIR
  int* posmap = (int*)(small + 3 * NPAIR * 4);     // NPAIR
  int* counts = (int*)(small + 4 * NPAIR * 4);     // 8
  int* fill = counts + 8;                          // 8

  hipMemsetAsync(counts, 0, 16 * sizeof(int), stream);

  transpose_cvt<<<dim3(I_DIM / 64, H_DIM / 64, E_NUM), 256, 0, stream>>>(w1, w1t, H_DIM, I_DIM);
  transpose_cvt<<<dim3(H_DIM / 64, I_DIM / 64, E_NUM), 256, 0, stream>>>(w2, w2t, I_DIM, H_DIM);

  router_kernel<<<T_TOK / 16, 256, 0, stream>>>(hs, gw, hsb, eid, wgt, counts);
  scatter_kernel<<<NPAIR / 256, 256, 0, stream>>>(eid, counts, fill, rowmap, posmap);

  moe_gemm<0, I_DIM / BN><<<MAX_RT * (I_DIM / BN), 256, 0, stream>>>(
      hsb, w1t, nullptr, act, nullptr, counts, rowmap, wgt);
  moe_gemm<1, H_DIM / BN><<<MAX_RT * (H_DIM / BN), 256, 0, stream>>>(
      hsb, w2t, act, nullptr, res, counts, rowmap, wgt);

  combine_kernel<<<T_TOK, 256, 0, stream>>>(res, posmap, out);
}

// Round 11
// 261.053 us; speedup vs baseline: 1.4227x; 1.0966x over previous
//
#include <hip/hip_runtime.h>
#include <hip/hip_bf16.h>

// ---------------- problem constants (match setup_inputs) ----------------
#define T_TOK 4096
#define H_DIM 1024
#define E_NUM 8
#define I_DIM 3584
#define NPAIR (T_TOK * 2)   // top_k = 2
#define MAX_RT 72           // worst-case total row tiles: sum ceil(cnt_e/128) <= 64+7

#define BM 128
#define BK 64

typedef __attribute__((ext_vector_type(8))) short bf16x8;
typedef __attribute__((ext_vector_type(4))) float f32x4;
typedef __attribute__((ext_vector_type(8))) unsigned short ushort8_t;
typedef __attribute__((ext_vector_type(4))) unsigned short ushort4_t;

// RNE fp32 -> bf16
__device__ __forceinline__ unsigned short f2bf(float x) {
  unsigned int u = __float_as_uint(x);
  unsigned int r = (u + 0x7FFFu + ((u >> 16) & 1u)) >> 16;
  return (unsigned short)r;
}

// async 16B global -> LDS (dest: wave-uniform base, HW adds lane*16)
__device__ __forceinline__ void gload16(const void* g, unsigned short* l) {
  __builtin_amdgcn_global_load_lds(
      (const __attribute__((address_space(1))) void*)g,
      (__attribute__((address_space(3))) void*)l, 16, 0, 0);
}

// ---------------- fused prep: both weight transposes + router --------------
// grid: [0,7168) w1 tiles | [7168,14336) w2 tiles | [14336,14592) router
__device__ __forceinline__ void transpose_body(const float* __restrict__ src,
                                               unsigned short* __restrict__ dst,
                                               int R, int C, int e, int c0, int r0,
                                               char* smem) {
  float (*tile)[65] = reinterpret_cast<float (*)[65]>(smem);
  const float* s = src + (size_t)e * R * C;
  unsigned short* d = dst + (size_t)e * R * C;
  const int th = threadIdx.x;
  const int tr = th >> 4;
  const int tc4 = (th & 15) * 4;
#pragma unroll
  for (int it = 0; it < 4; ++it) {
    const int r = it * 16 + tr;
    float4 v = *reinterpret_cast<const float4*>(s + (size_t)(r0 + r) * C + c0 + tc4);
    tile[r][tc4] = v.x; tile[r][tc4 + 1] = v.y; tile[r][tc4 + 2] = v.z; tile[r][tc4 + 3] = v.w;
  }
  __syncthreads();
  const int wc = th >> 3;
  const int wr = (th & 7) * 8;
#pragma unroll
  for (int it = 0; it < 2; ++it) {
    const int c = it * 32 + wc;
    ushort8_t o;
#pragma unroll
    for (int j = 0; j < 8; ++j) o[j] = f2bf(tile[wr + j][c]);
    *reinterpret_cast<ushort8_t*>(d + (size_t)(c0 + c) * R + r0 + wr) = o;
  }
}

__device__ __forceinline__ void router_body(const float* __restrict__ hs,
                                            const float* __restrict__ gw,
                                            unsigned short* __restrict__ hsb,
                                            int* __restrict__ eid, float* __restrict__ wgt,
                                            int* __restrict__ counts, int rbid, char* smem) {
  float* s_gw = reinterpret_cast<float*>(smem);          // 32 KB
  int* s_cnt = reinterpret_cast<int*>(smem + 32768);     // 32 B
  const int th = threadIdx.x;
  for (int u = th; u < 2048; u += 256) {
    const f32x4 v = *reinterpret_cast<const f32x4*>(gw + u * 4);
    *reinterpret_cast<f32x4*>(&s_gw[(u ^ ((u >> 3) & 7)) * 4]) = v;
  }
  if (th < E_NUM) s_cnt[th] = 0;
  __syncthreads();

  const int l = th & 63, w = th >> 6;
#pragma unroll 1
  for (int tt = 0; tt < 4; ++tt) {
    const int t = rbid * 16 + w * 4 + tt;
    const float* hrow = hs + (size_t)t * H_DIM;
    unsigned short* brow = hsb + (size_t)t * H_DIM;
    float acc[E_NUM];
#pragma unroll
    for (int e = 0; e < E_NUM; ++e) acc[e] = 0.f;
#pragma unroll
    for (int i = 0; i < 4; ++i) {
      const int h0 = i * 256 + l * 4;
      const f32x4 x = *reinterpret_cast<const f32x4*>(hrow + h0);
      ushort4_t o = { f2bf(x[0]), f2bf(x[1]), f2bf(x[2]), f2bf(x[3]) };
      *reinterpret_cast<ushort4_t*>(brow + h0) = o;
#pragma unroll
      for (int j = 0; j < 4; ++j) {
        const int h = h0 + j;
        const int p0 = (h * 2) ^ ((h >> 2) & 7);
        const f32x4 g0 = *reinterpret_cast<const f32x4*>(&s_gw[p0 * 4]);
        const f32x4 g1 = *reinterpret_cast<const f32x4*>(&s_gw[(p0 ^ 1) * 4]);
        acc[0] += x[j] * g0[0]; acc[1] += x[j] * g0[1];
        acc[2] += x[j] * g0[2]; acc[3] += x[j] * g0[3];
        acc[4] += x[j] * g1[0]; acc[5] += x[j] * g1[1];
        acc[6] += x[j] * g1[2]; acc[7] += x[j] * g1[3];
      }
    }
#pragma unroll
    for (int e = 0; e < E_NUM; ++e) {
#pragma unroll
      for (int off = 1; off < 64; off <<= 1) acc[e] += __shfl_xor(acc[e], off);
    }
    if (l == 0) {
      int i1 = 0;
#pragma unroll
      for (int e = 1; e < E_NUM; ++e) if (acc[e] > acc[i1]) i1 = e;
      int i2 = (i1 == 0) ? 1 : 0;
#pragma unroll
      for (int e = 0; e < E_NUM; ++e) if (e != i1 && acc[e] > acc[i2]) i2 = e;
      const float e2 = __expf(acc[i2] - acc[i1]);
      const float inv = 1.f / (1.f + e2);
      eid[t * 2] = i1;     wgt[t * 2] = inv;
      eid[t * 2 + 1] = i2; wgt[t * 2 + 1] = e2 * inv;
      atomicAdd(&s_cnt[i1], 1);
      atomicAdd(&s_cnt[i2], 1);
    }
  }
  __syncthreads();
  if (th < E_NUM && s_cnt[th] > 0) atomicAdd(&counts[th], s_cnt[th]);
}

__global__ __launch_bounds__(256) void prep_kernel(
    const float* __restrict__ w1, const float* __restrict__ w2,
    const float* __restrict__ hs, const float* __restrict__ gw,
    unsigned short* __restrict__ w1t, unsigned short* __restrict__ w2t,
    unsigned short* __restrict__ hsb,
    int* __restrict__ eid, float* __restrict__ wgt, int* __restrict__ counts) {
  __shared__ char smem[33024];   // router: 32KB + 32B; transpose: 16.6KB
  const int bid = blockIdx.x;
  if (bid < 7168) {
    // w1: R=H=1024, C=I=3584; tiles per e = 56 x 16
    const int e = bid / 896, rem = bid % 896;
    transpose_body(w1, w1t, H_DIM, I_DIM, e, (rem % 56) * 64, (rem / 56) * 64, smem);
  } else if (bid < 14336) {
    // w2: R=I=3584, C=H=1024; tiles per e = 16 x 56
    const int idx = bid - 7168;
    const int e = idx / 896, rem = idx % 896;
    transpose_body(w2, w2t, I_DIM, H_DIM, e, (rem % 16) * 64, (rem / 16) * 64, smem);
  } else {
    router_body(hs, gw, hsb, eid, wgt, counts, bid - 14336, smem);
  }
}

// ---------------- scatter: block-local histogram + range reservation -------
__global__ void scatter_kernel(const int* __restrict__ eid, const int* __restrict__ counts,
                               int* __restrict__ fill, int* __restrict__ rowmap,
                               int* __restrict__ posmap) {
  __shared__ int hist[E_NUM], base[E_NUM];
  const int th = threadIdx.x;
  const int p = blockIdx.x * 256 + th;
  if (th < E_NUM) hist[th] = 0;
  __syncthreads();
  const int e = eid[p];
  const int rloc = atomicAdd(&hist[e], 1);
  __syncthreads();
  if (th < E_NUM) base[th] = (hist[th] > 0) ? atomicAdd(&fill[th], hist[th]) : 0;
  __syncthreads();
  int off = 0;
#pragma unroll
  for (int i = 0; i < E_NUM; ++i) off += (i < e) ? counts[i] : 0;
  const int pos = off + base[e] + rloc;
  rowmap[pos] = p;
  posmap[p] = pos;
}

// ---------------- combine: out[t] = res[pos(2t)] + res[pos(2t+1)] ----------
__global__ void combine_kernel(const float* __restrict__ res, const int* __restrict__ posmap,
                               float* __restrict__ out) {
  const int t = blockIdx.x;
  const int th = threadIdx.x;
  const int a = posmap[t * 2];
  const int b = posmap[t * 2 + 1];
  const float4 va = *reinterpret_cast<const float4*>(res + (size_t)a * H_DIM + th * 4);
  const float4 vb = *reinterpret_cast<const float4*>(res + (size_t)b * H_DIM + th * 4);
  float4 o = { va.x + vb.x, va.y + vb.y, va.z + vb.z, va.w + vb.w };
  *reinterpret_cast<float4*>(out + (size_t)t * H_DIM + th * 4) = o;
}

// ---------------- grouped GEMM (R6 structure; ct-fast XCD swizzle) ---------
// MODE 0: BN=128, 2x2 waves of 64x64. A = gathered hs bf16, B = w1t, silu->act
// MODE 1: BN=64, 4 waves of 32x64 (grid 1152 for occupancy). plain res stores
template <int MODE, int NCT, int OCC>
__launch_bounds__(256, OCC)
__global__ void moe_gemm(const unsigned short* __restrict__ hsb,
                         const unsigned short* __restrict__ wt,
                         const unsigned short* __restrict__ act_in,
                         unsigned short* __restrict__ act_out,
                         float* __restrict__ res,
                         const int* __restrict__ counts,
                         const int* __restrict__ rowmap,
                         const float* __restrict__ wgt) {
  constexpr int KD = (MODE == 0) ? H_DIM : I_DIM;
  constexpr int BN_ = (MODE == 0) ? 128 : 64;
  constexpr int MFR = (MODE == 0) ? 4 : 2;   // 16-row m-frags per wave
  constexpr int NBR = BN_ / 32;              // B staging row-groups
  constexpr int NWG = MAX_RT * NCT;          // 2016 / 1152, %8==0

  __shared__ unsigned short As[BM * BK];
  __shared__ unsigned short Bs[BN_ * BK];
  __shared__ float s_w[BM];

  // T1 bijective XCD swizzle, ct FAST within chunk: A-tile stays L2-resident
  const int bid = blockIdx.x;
  const int wgid = (bid & 7) * (NWG / 8) + (bid >> 3);
  const int rt = wgid / NCT;
  const int ct = wgid % NCT;

  // expert walk from counts (prefix on the fly)
  int e = -1, loc_rt = 0, off_e = 0, cnt = 0;
  {
    int acc_t = 0, off = 0;
#pragma unroll
    for (int ee = 0; ee < E_NUM; ++ee) {
      const int c = counts[ee];
      const int nt = (c + BM - 1) >> 7;
      if (e < 0 && rt < acc_t + nt) { e = ee; loc_rt = rt - acc_t; off_e = off; cnt = c; }
      acc_t += nt; off += c;
    }
  }
  if (e < 0) return;

  const int cnt_local = min(BM, cnt - loc_rt * BM);
  const int r_base = off_e + loc_rt * BM;
  const int th = threadIdx.x;
  const int lane = th & 63, wid = th >> 6;

  if (MODE == 1 && th < BM) {
    int r = loc_rt * BM + th;
    if (r >= cnt) r = cnt - 1;
    s_w[th] = wgt[rowmap[off_e + r]];
  }

  const int n0 = ct * BN_;
  const unsigned short* wbase = wt + (size_t)e * ((size_t)I_DIM * H_DIM) + (size_t)n0 * KD;

  // staging geometry: lane covers (row-group + lane/8, chunk = lane%8)
  // LDS dest linear; source chunk pre-swizzled: cg = (lane&7) ^ (row&7)
  const int srow = lane >> 3;
  const int cg = (lane & 7) ^ srow;
  const char* aptr[4];
  const char* bptr[NBR];
#pragma unroll
  for (int i = 0; i < 4; ++i) {
    const int r = i * 32 + wid * 8 + srow;
    const int rr = (r < cnt_local) ? r : (cnt_local - 1);
    if (MODE == 0) {
      const int tok = rowmap[off_e + loc_rt * BM + rr] >> 1;
      aptr[i] = (const char*)(hsb + (size_t)tok * H_DIM) + cg * 16;
    } else {
      aptr[i] = (const char*)(act_in + (size_t)(r_base + rr) * I_DIM) + cg * 16;
    }
  }
#pragma unroll
  for (int j = 0; j < NBR; ++j) {
    const int r = j * 32 + wid * 8 + srow;
    bptr[j] = (const char*)(wbase + (size_t)r * KD) + cg * 16;
  }
  unsigned short* dstA[4];
  unsigned short* dstB[NBR];
#pragma unroll
  for (int i = 0; i < 4; ++i) dstA[i] = &As[(i * 32 + wid * 8) * BK];
#pragma unroll
  for (int j = 0; j < NBR; ++j) dstB[j] = &Bs[(j * 32 + wid * 8) * BK];

  f32x4 acc[MFR][4];
#pragma unroll
  for (int m = 0; m < MFR; ++m)
#pragma unroll
    for (int n = 0; n < 4; ++n) acc[m][n] = (f32x4){0.f, 0.f, 0.f, 0.f};

  const int wm = (MODE == 0) ? (wid >> 1) * 64 : wid * 32;
  const int wn = (MODE == 0) ? (wid & 1) * 64 : 0;
  const int fr = lane & 15;
  const int fq = lane >> 4;
  const int sxor = fr & 7;

  for (int k0 = 0; k0 < KD; k0 += BK) {
    const int kb = k0 * 2;
#pragma unroll
    for (int i = 0; i < 4; ++i) gload16(aptr[i] + kb, dstA[i]);
#pragma unroll
    for (int j = 0; j < NBR; ++j) gload16(bptr[j] + kb, dstB[j]);
    __syncthreads();   // drains vmcnt before s_barrier

#pragma unroll
    for (int kk = 0; kk < 2; ++kk) {
      bf16x8 af[MFR], bf[4];
#pragma unroll
      for (int m = 0; m < MFR; ++m)
        af[m] = *reinterpret_cast<const bf16x8*>(
            &As[(wm + m * 16 + fr) * BK + ((kk * 4 + fq) ^ sxor) * 8]);
#pragma unroll
      for (int n = 0; n < 4; ++n)
        bf[n] = *reinterpret_cast<const bf16x8*>(
            &Bs[(wn + n * 16 + fr) * BK + ((kk * 4 + fq) ^ sxor) * 8]);
#pragma unroll
      for (int m = 0; m < MFR; ++m)
#pragma unroll
        for (int n = 0; n < 4; ++n)
          acc[m][n] = __builtin_amdgcn_mfma_f32_16x16x32_bf16(af[m], bf[n], acc[m][n], 0, 0, 0);
    }
    __syncthreads();
  }

  // ---- epilogue ----
#pragma unroll
  for (int m = 0; m < MFR; ++m) {
    const int row = wm + m * 16 + fq * 4;
#pragma unroll
    for (int n = 0; n < 4; ++n) {
      const int col = wn + n * 16 + fr;
#pragma unroll
      for (int r = 0; r < 4; ++r) {
        const int rw = row + r;
        if (rw < cnt_local) {
          const float x = acc[m][n][r];
          if (MODE == 0) {
            const float s = x / (1.f + __expf(-x));   // silu
            act_out[(size_t)(r_base + rw) * I_DIM + n0 + col] = f2bf(s);
          } else {
            res[(size_t)(r_base + rw) * H_DIM + n0 + col] = x * s_w[rw];
          }
        }
      }
    }
  }
}

// ---------------- launch ----------------
extern "C" void kernel_launch(void* const* d_in, const int* in_sizes, int n_in,
                              void* d_out, int out_size, void* d_ws, size_t ws_size,
                              hipStream_t stream) {
  const float* hs = (const float*)d_in[0];
  const float* gw = (const float*)d_in[1];
  const float* w1 = (const float*)d_in[2];
  const float* w2 = (const float*)d_in[3];
  float* out = (float*)d_out;

  char* ws = (char*)d_ws;
  const size_t WMAT = (size_t)E_NUM * I_DIM * H_DIM * 2;   // 58,720,256 B
  unsigned short* w1t = (unsigned short*)ws;                // [E][I][H] bf16
  unsigned short* w2t = (unsigned short*)(ws + WMAT);       // [E][H][I] bf16
  unsigned short* act = (unsigned short*)(ws + 2 * WMAT);   // [NPAIR][I] bf16
  unsigned short* hsb = (unsigned short*)(ws + 3 * WMAT);   // [T][H] bf16
  // res aliases w1t: dead after MODE0 completes (stream-ordered, race-free).
  float* res = (float*)w1t;                                 // [NPAIR][H] fp32 (32MB <= 58.7MB)
  char* small = ws + 3 * WMAT + (size_t)T_TOK * H_DIM * 2;
  int* eid = (int*)small;                          // NPAIR
  float* wgt = (float*)(small + NPAIR * 4);        // NPAIR
  int* rowmap = (int*)(small + 2 * NPAIR * 4);     // NPAIR
  int* posmap = (int*)(small + 3 * NPAIR * 4);     // NPAIR
  int* counts = (int*)(small + 4 * NPAIR * 4);     // 8
  int* fill = counts + 8;                          // 8

  hipMemsetAsync(counts, 0, 16 * sizeof(int), stream);

  prep_kernel<<<14592, 256, 0, stream>>>(w1, w2, hs, gw, w1t, w2t, hsb, eid, wgt, counts);
  scatter_kernel<<<NPAIR / 256, 256, 0, stream>>>(eid, counts, fill, rowmap, posmap);

  moe_gemm<0, I_DIM / 128, 4><<<MAX_RT * (I_DIM / 128), 256, 0, stream>>>(
      hsb, w1t, nullptr, act, nullptr, counts, rowmap, wgt);
  moe_gemm<1, H_DIM / 64, 5><<<MAX_RT * (H_DIM / 64), 256, 0, stream>>>(
      hsb, w2t, act, nullptr, res, counts, rowmap, wgt);

  combine_kernel<<<T_TOK, 256, 0, stream>>>(res, posmap, out);
}